// Round 15
// baseline (596.346 us; speedup 1.0000x reference)
//
#include <hip/hip_runtime.h>
#include <hip/hip_bf16.h>
#include <stdint.h>

#define T_SEQ 4096
#define C_ST  1024
#define K2    2048
#define K3    3072
#define NB    4
#define NCHUNK 128
#define CHUNK  32

typedef __bf16 bf16x8_t __attribute__((ext_vector_type(8)));
typedef float f32x4_t __attribute__((ext_vector_type(4)));
typedef unsigned short u16x8 __attribute__((ext_vector_type(8)));
typedef unsigned short u16x4 __attribute__((ext_vector_type(4)));
typedef __attribute__((address_space(1))) unsigned int as1u32;
typedef __attribute__((address_space(3))) unsigned int as3u32;

__device__ __forceinline__ unsigned short bfbits(float f) {
  __hip_bfloat16 h = __float2bfloat16(f);
  return *reinterpret_cast<unsigned short*>(&h);
}
__device__ __forceinline__ float bf2f(unsigned short u) {
  __hip_bfloat16 h;
  *reinterpret_cast<unsigned short*>(&h) = u;
  return __bfloat162float(h);
}
__device__ __forceinline__ float phi_f(float x) {
  // silu(x) + 1
  return x / (1.0f + __expf(-x)) + 1.0f;
}

// ---------------------------------------------------------------------------
// Weight prep: all four W (1024x1024 f32) -> rows of K2=2048 bf16: [Wh | Wh]
// ---------------------------------------------------------------------------
__global__ __launch_bounds__(256) void conv_w_kernel(
    const float* __restrict__ Wq, const float* __restrict__ Wk,
    const float* __restrict__ Wv, const float* __restrict__ Wo,
    unsigned short* __restrict__ W3, unsigned short* __restrict__ Wo3) {
  int r = blockIdx.x;
  int which = blockIdx.y;
  const float* src = (which == 0) ? Wq : (which == 1) ? Wk : (which == 2) ? Wv : Wo;
  unsigned short* dst = (which < 3) ? (W3 + (size_t)(which * 1024 + r) * K2)
                                    : (Wo3 + (size_t)r * K2);
  int c4 = threadIdx.x * 4;
  float4 v = *reinterpret_cast<const float4*>(&src[(size_t)r * 1024 + c4]);
  float fe[4] = {v.x, v.y, v.z, v.w};
  u16x4 hh;
#pragma unroll
  for (int e = 0; e < 4; ++e) hh[e] = bfbits(fe[e]);
  *reinterpret_cast<u16x4*>(&dst[c4])        = hh;
  *reinterpret_cast<u16x4*>(&dst[1024 + c4]) = hh;
}

// ---------------------------------------------------------------------------
// x prep: x (B,C,T) f32 -> xT (z,T,2C) bf16 [xh | xl]; grid (T/64, C/64, PB)
// ---------------------------------------------------------------------------
__global__ __launch_bounds__(256) void conv_x_kernel(
    const float* __restrict__ x0, unsigned short* __restrict__ xT0) {
  __shared__ float tile[64][65];
  int c0 = blockIdx.y * 64, t0 = blockIdx.x * 64, z = blockIdx.z;
  const float* xb = x0 + (size_t)z * C_ST * T_SEQ + (size_t)c0 * T_SEQ + t0;
  unsigned short* xT = xT0 + (size_t)z * T_SEQ * K2;
  int tid = threadIdx.x;
#pragma unroll
  for (int p = 0; p < 4; ++p) {
    int idx = tid + p * 256;
    int r = idx >> 4, q4 = (idx & 15) * 4;
    float4 v = *reinterpret_cast<const float4*>(&xb[(size_t)r * T_SEQ + q4]);
    tile[r][q4 + 0] = v.x; tile[r][q4 + 1] = v.y;
    tile[r][q4 + 2] = v.z; tile[r][q4 + 3] = v.w;
  }
  __syncthreads();
  int r = tid >> 2, q = (tid & 3) * 16;
  u16x8 h0, h1, l0, l1;
#pragma unroll
  for (int j = 0; j < 8; ++j) {
    float f = tile[q + j][r];
    unsigned short hb = bfbits(f);
    h0[j] = hb; l0[j] = bfbits(f - bf2f(hb));
  }
#pragma unroll
  for (int j = 0; j < 8; ++j) {
    float f = tile[q + 8 + j][r];
    unsigned short hb = bfbits(f);
    h1[j] = hb; l1[j] = bfbits(f - bf2f(hb));
  }
  unsigned short* dst = xT + ((size_t)(t0 + r)) * K2 + c0 + q;
  *reinterpret_cast<u16x8*>(dst)         = h0;
  *reinterpret_cast<u16x8*>(dst + 8)     = h1;
  *reinterpret_cast<u16x8*>(dst + 1024)  = l0;
  *reinterpret_cast<u16x8*>(dst + 1032)  = l1;
}

// ---------------------------------------------------------------------------
// gemm_bt: acc[m][n] = sum_k A[m][k]*B[n][k]; z-batched via strides.
// 128x128 tile, BK=64, 4 waves (2x2), 16x16x32 MFMA, global_load_lds w16,
// lane-permutation swizzle (proven r12/r13).
// Epilogue modes:
//   mode 0: f32 out, + biasRow[row]              (output GEMM)
//   mode 1: bf16 out with fused activation by column plane:
//           col<1024: phi(val+bq[col]) ; col<2048: phi(val) ; else val+bv[col-2048]
// ---------------------------------------------------------------------------
__global__ __launch_bounds__(256) void gemm_bt_kernel(
    const unsigned short* __restrict__ A, const unsigned short* __restrict__ B,
    void* __restrict__ Cout, const float* __restrict__ biasRow,
    const float* __restrict__ bq, const float* __restrict__ bv,
    int M, int N, int K, long long sA, long long sB, long long sC, int mode) {
  __shared__ unsigned short As[128 * 64];
  __shared__ unsigned short Bs[128 * 64];
  int z = blockIdx.z;
  const unsigned short* Ab = A + (size_t)z * sA;
  const unsigned short* Bb = B + (size_t)z * sB;
  int m0 = blockIdx.y * 128, n0 = blockIdx.x * 128;
  int tid = threadIdx.x, lane = tid & 63, wid = tid >> 6;
  int wr = wid >> 1, wc = wid & 1;
  int l16 = lane & 15, l4 = lane >> 4;
  int seg_src = (lane & 7) ^ ((lane >> 3) & 7);
  f32x4_t acc[4][4] = {};

  for (int k0 = 0; k0 < K; k0 += 64) {
    __syncthreads();
#pragma unroll
    for (int s = 0; s < 4; ++s) {
      int chunk = wid * 4 + s;              // 1KB = rows 8c..8c+7
      int row = chunk * 8 + (lane >> 3);
      const unsigned short* ga = Ab + (size_t)(m0 + row) * K + k0 + seg_src * 8;
      const unsigned short* gb = Bb + (size_t)(n0 + row) * K + k0 + seg_src * 8;
      __builtin_amdgcn_global_load_lds((as1u32*)ga, (as3u32*)(As + chunk * 512), 16, 0, 0);
      __builtin_amdgcn_global_load_lds((as1u32*)gb, (as3u32*)(Bs + chunk * 512), 16, 0, 0);
    }
    __syncthreads();
#pragma unroll
    for (int s2 = 0; s2 < 2; ++s2) {
      bf16x8_t af[4], bfr[4];
      int kseg = s2 * 4 + l4;
#pragma unroll
      for (int m = 0; m < 4; ++m) {
        int r = wr * 64 + m * 16 + l16;
        af[m] = *reinterpret_cast<const bf16x8_t*>(&As[r * 64 + (kseg ^ (r & 7)) * 8]);
      }
#pragma unroll
      for (int n = 0; n < 4; ++n) {
        int r = wc * 64 + n * 16 + l16;
        bfr[n] = *reinterpret_cast<const bf16x8_t*>(&Bs[r * 64 + (kseg ^ (r & 7)) * 8]);
      }
#pragma unroll
      for (int m = 0; m < 4; ++m)
#pragma unroll
        for (int n = 0; n < 4; ++n)
          acc[m][n] = __builtin_amdgcn_mfma_f32_16x16x32_bf16(af[m], bfr[n], acc[m][n], 0, 0, 0);
    }
  }

  if (mode == 0) {
    float* Cb = (float*)Cout + (size_t)z * sC;
#pragma unroll
    for (int m = 0; m < 4; ++m)
#pragma unroll
      for (int n = 0; n < 4; ++n) {
        int row = m0 + wr * 64 + m * 16 + l4 * 4;
        int col = n0 + wc * 64 + n * 16 + l16;
#pragma unroll
        for (int j = 0; j < 4; ++j)
          Cb[(size_t)(row + j) * N + col] = acc[m][n][j] + biasRow[row + j];
      }
  } else {
    unsigned short* Cb = (unsigned short*)Cout + (size_t)z * sC;
#pragma unroll
    for (int m = 0; m < 4; ++m)
#pragma unroll
      for (int n = 0; n < 4; ++n) {
        int row = m0 + wr * 64 + m * 16 + l4 * 4;
        int col = n0 + wc * 64 + n * 16 + l16;
#pragma unroll
        for (int j = 0; j < 4; ++j) {
          float val = acc[m][n][j];
          if (col < 1024)       val = phi_f(val + bq[col]);
          else if (col < 2048)  val = phi_f(val);
          else                  val = val + bv[col - 2048];
          Cb[(size_t)(row + j) * N + col] = bfbits(val);
        }
      }
  }
}

// ---------------------------------------------------------------------------
// Scan A: per-chunk totals of K~ and K~*V~ (phi already fused in GEMM1).
// grid (NCHUNK/4, 16, PB), 256 thr = 4 waves; 8x-unrolled bf16 loads.
// ---------------------------------------------------------------------------
__global__ __launch_bounds__(256) void scan_a_kernel(
    const unsigned short* __restrict__ qkv0,
    float* __restrict__ partK, float* __restrict__ partKV) {
  int d = threadIdx.x & 63;
  int w = threadIdx.x >> 6;
  int ch = blockIdx.x * 4 + w, h = blockIdx.y, z = blockIdx.z;
  int c = h * 64 + d;
  const unsigned short* base = qkv0 + (size_t)z * T_SEQ * K3 + (size_t)ch * CHUNK * K3;
  float sk = 0.f, skv = 0.f;
  for (int tt = 0; tt < CHUNK; tt += 8) {
    float kt[8], vt[8];
#pragma unroll
    for (int u = 0; u < 8; ++u) {
      const unsigned short* row = base + (size_t)(tt + u) * K3;
      kt[u] = bf2f(row[1024 + c]);
      vt[u] = bf2f(row[2048 + c]);
    }
#pragma unroll
    for (int u = 0; u < 8; ++u) { sk += kt[u]; skv += kt[u] * vt[u]; }
  }
  size_t pidx = (((size_t)z * 16 + h) * NCHUNK + ch) * 64 + d;
  partK[pidx] = sk;
  partKV[pidx] = skv;
}

// Scan B: exclusive prefix over chunks. grid (16, PB), 64 threads.
__global__ void scan_b_kernel(float* __restrict__ partK, float* __restrict__ partKV) {
  int d = threadIdx.x;
  int h = blockIdx.x, z = blockIdx.y;
  size_t base = ((size_t)z * 16 + h) * NCHUNK * 64 + d;
  float rk = 0.f, rkv = 0.f;
  for (int ch = 0; ch < NCHUNK; ++ch) {
    size_t i = base + (size_t)ch * 64;
    float tk = partK[i], tkv = partKV[i];
    partK[i] = rk; partKV[i] = rkv;
    rk += tk; rkv += tkv;
  }
}

// Scan C: emit attention output, 2-term split [oh | ol] (K2 stride).
// grid (NCHUNK/4, 16, PB), 256 thr = 4 waves; 8x unroll, no transcendentals.
__global__ __launch_bounds__(256) void scan_c_kernel(
    const unsigned short* __restrict__ qkv0,
    const float* __restrict__ partK, const float* __restrict__ partKV,
    unsigned short* __restrict__ outT0) {
  int d = threadIdx.x & 63;
  int w = threadIdx.x >> 6;
  int ch = blockIdx.x * 4 + w, h = blockIdx.y, z = blockIdx.z;
  int c = h * 64 + d;
  size_t pidx = (((size_t)z * 16 + h) * NCHUNK + ch) * 64 + d;
  float sk = partK[pidx], skv = partKV[pidx];
  const unsigned short* base = qkv0 + (size_t)z * T_SEQ * K3 + (size_t)ch * CHUNK * K3;
  unsigned short* obase = outT0 + (size_t)z * T_SEQ * K2 + (size_t)ch * CHUNK * K2;
  for (int tt = 0; tt < CHUNK; tt += 8) {
    float pq[8], kt[8], vt[8];
#pragma unroll
    for (int u = 0; u < 8; ++u) {
      const unsigned short* row = base + (size_t)(tt + u) * K3;
      pq[u] = bf2f(row[c]);
      kt[u] = bf2f(row[1024 + c]);
      vt[u] = bf2f(row[2048 + c]);
    }
    float dp[8], skv_s[8];
#pragma unroll
    for (int u = 0; u < 8; ++u) {
      sk += kt[u]; skv += kt[u] * vt[u];
      dp[u] = pq[u] * sk;
      skv_s[u] = skv;
    }
#pragma unroll
    for (int off = 32; off > 0; off >>= 1)
#pragma unroll
      for (int u = 0; u < 8; ++u) dp[u] += __shfl_xor(dp[u], off);
#pragma unroll
    for (int u = 0; u < 8; ++u) {
      float o = pq[u] * skv_s[u] / (dp[u] + 1e-6f) * 0.125f;  // 1/sqrt(64)
      unsigned short oh = bfbits(o);
      unsigned short ol = bfbits(o - bf2f(oh));
      unsigned short* orow = obase + (size_t)(tt + u) * K2;
      orow[c] = oh; orow[1024 + c] = ol;
    }
  }
}

// ---------------------------------------------------------------------------
extern "C" void kernel_launch(void* const* d_in, const int* in_sizes, int n_in,
                              void* d_out, int out_size, void* d_ws, size_t ws_size,
                              hipStream_t stream) {
  const float* x  = (const float*)d_in[0];
  const float* Wq = (const float*)d_in[1];
  const float* bq = (const float*)d_in[2];
  const float* Wk = (const float*)d_in[3];
  const float* Wv = (const float*)d_in[4];
  const float* bv = (const float*)d_in[5];
  const float* Wo = (const float*)d_in[6];
  const float* bo = (const float*)d_in[7];
  float* out = (float*)d_out;

  // Workspace (PB = batches pipelined):
  //   W3   @ 0          : 12,582,912
  //   Wo3  @ 12,582,912 :  4,194,304
  //   xT   @ 16,777,216 : PB * 16,777,216  (T*K2 bf16; also holds [oh|ol])
  //   qkv  @ +PB*xT     : PB * 25,165,824  (T*K3 bf16, phi-fused planes)
  //   partK/partKV      : PB * 524,288 each
  const size_t BASE = 16777216;
  const size_t PER  = 16777216ULL + 25165824ULL + 2 * 524288ULL;  // 43.0 MB
  int PB = (ws_size >= BASE + 4 * PER) ? 4 : (ws_size >= BASE + 2 * PER) ? 2
         : (ws_size >= BASE + 1 * PER) ? 1 : 0;
  if (PB == 0) return;

  char* w = (char*)d_ws;
  unsigned short* W3     = (unsigned short*)(w);
  unsigned short* Wo3    = (unsigned short*)(w + 12582912);
  unsigned short* xT     = (unsigned short*)(w + BASE);
  unsigned short* qkv    = (unsigned short*)(w + BASE + (size_t)PB * 16777216);
  float*          partK  = (float*)(w + BASE + (size_t)PB * 41943040);
  float*          partKV = (float*)(w + BASE + (size_t)PB * 41943040 + (size_t)PB * 524288);

  // 1) weight prep (once)
  conv_w_kernel<<<dim3(1024, 4), 256, 0, stream>>>(Wq, Wk, Wv, Wo, W3, Wo3);

  for (int g = 0; g < NB; g += PB) {
    const float* xg = x + (size_t)g * C_ST * T_SEQ;
    float* outg = out + (size_t)g * C_ST * T_SEQ;
    // 2) x transpose + 2-term split
    conv_x_kernel<<<dim3(T_SEQ / 64, C_ST / 64, PB), 256, 0, stream>>>(xg, xT);
    // 3) fused QKV GEMM (K=2048) with phi/bias epilogue -> bf16 planes
    gemm_bt_kernel<<<dim3(K3 / 128, T_SEQ / 128, PB), 256, 0, stream>>>(
        xT, W3, qkv, nullptr, bq, bv, T_SEQ, K3, K2,
        (long long)T_SEQ * K2, 0LL, (long long)T_SEQ * K3, 1);
    // 4) chunked scan; scan_c writes [oh|ol] into xT (dead after GEMM1)
    scan_a_kernel<<<dim3(NCHUNK / 4, 16, PB), 256, 0, stream>>>(qkv, partK, partKV);
    scan_b_kernel<<<dim3(16, PB), 64, 0, stream>>>(partK, partKV);
    scan_c_kernel<<<dim3(NCHUNK / 4, 16, PB), 256, 0, stream>>>(qkv, partK, partKV, xT);
    // 5) output GEMM (K=2048): out = Wo*o + bo
    gemm_bt_kernel<<<dim3(T_SEQ / 128, C_ST / 128, PB), 256, 0, stream>>>(
        Wo3, xT, outg, bo, nullptr, nullptr, C_ST, T_SEQ, K2,
        0LL, (long long)T_SEQ * K2, (long long)C_ST * T_SEQ, 0);
  }
}